// Round 6
// baseline (237.543 us; speedup 1.0000x reference)
//
#include <hip/hip_runtime.h>

// NSA constants
#define NCMP 127
#define SCALE 0.08838834764831845f
#define QSCALE (0.08838834764831845f * 1.4426950408889634f)  // SCALE * log2(e)
#define TB 8    // t's per WG in k_cmp_attn

typedef __attribute__((ext_vector_type(8))) short bf16x8;
typedef __attribute__((ext_vector_type(4))) float f32x4;

__device__ __forceinline__ unsigned short f2bf(float x) {
    union { float f; unsigned u; } a; a.f = x;
    unsigned r = a.u + 0x7fffu + ((a.u >> 16) & 1u);
    return (unsigned short)(r >> 16);
}
__device__ __forceinline__ float dot4(float4 a, float4 b) {
    return a.x * b.x + a.y * b.y + a.z * b.z + a.w * b.w;
}

// ------------- Kernel A: fused k+v compress (gate-pooled blocks) -------------
__global__ __launch_bounds__(256) void k_compress2(const float* __restrict__ kk,
                                                   const float* __restrict__ vv,
                                                   const float* __restrict__ wk,
                                                   const float* __restrict__ wv,
                                                   float* __restrict__ ck,
                                                   float* __restrict__ cv) {
    __shared__ float blk[4096];   // 32 x 128 f32
    __shared__ float gate[32];
    int n = blockIdx.x >> 1;
    int which = blockIdx.x & 1;
    const float* src = which ? vv : kk;
    const float* w   = which ? wv : wk;
    float* out       = which ? cv : ck;
    int tid = threadIdx.x;

    {
        const float4* sp = reinterpret_cast<const float4*>(src + n * 16 * 128);
        float4* bp = reinterpret_cast<float4*>(blk);
        #pragma unroll
        for (int i = 0; i < 4; ++i) bp[tid + 256 * i] = sp[tid + 256 * i];
    }
    __syncthreads();

    {
        int j = tid >> 3, sub = tid & 7;
        const float4* wp = reinterpret_cast<const float4*>(w + j * 4096);
        const float4* bp = reinterpret_cast<const float4*>(blk);
        float s0 = 0.f, s1 = 0.f, s2 = 0.f, s3 = 0.f;
        for (int i = sub * 4; i < 1024; i += 32) {
            float4 w0 = wp[i], w1 = wp[i + 1], w2 = wp[i + 2], w3 = wp[i + 3];
            s0 += dot4(bp[i], w0);
            s1 += dot4(bp[i + 1], w1);
            s2 += dot4(bp[i + 2], w2);
            s3 += dot4(bp[i + 3], w3);
        }
        float s = (s0 + s1) + (s2 + s3);
        s += __shfl_xor(s, 1);
        s += __shfl_xor(s, 2);
        s += __shfl_xor(s, 4);
        if (sub == 0) gate[j] = s;
    }
    __syncthreads();

    if (tid < 32) {
        float gv = gate[tid];
        float m = gv;
        #pragma unroll
        for (int off = 16; off > 0; off >>= 1) m = fmaxf(m, __shfl_xor(m, off));
        float e = expf(gv - m);
        float ss = e;
        #pragma unroll
        for (int off = 16; off > 0; off >>= 1) ss += __shfl_xor(ss, off);
        gate[tid] = e / ss;
    }
    __syncthreads();

    if (tid < 128) {
        float acc = 0.f;
        #pragma unroll
        for (int kx = 0; kx < 32; ++kx) acc += gate[kx] * blk[kx * 128 + tid];
        out[n * 128 + tid] = acc;
    }
}

// ------------- Kernel D: f32 -> bf16 convert (K row-major, V transposed) -------------
__global__ __launch_bounds__(256) void k_convert(const float* __restrict__ k,
                                                 const float* __restrict__ v,
                                                 unsigned short* __restrict__ kbf,
                                                 unsigned short* __restrict__ vtbf) {
    int bid = blockIdx.x, tid = threadIdx.x;
    {
        int idx = bid * 1024 + tid * 4;
        float4 x = *reinterpret_cast<const float4*>(k + idx);
        unsigned short o[4] = {f2bf(x.x), f2bf(x.y), f2bf(x.z), f2bf(x.w)};
        *reinterpret_cast<ulonglong1*>(kbf + idx) = *reinterpret_cast<ulonglong1*>(o);
    }
    {
        int p = bid * 8 + (tid >> 5);
        int d4 = (tid & 31) << 2;
        float4 x = *reinterpret_cast<const float4*>(v + p * 128 + d4);
        vtbf[(d4 + 0) * 2048 + p] = f2bf(x.x);
        vtbf[(d4 + 1) * 2048 + p] = f2bf(x.y);
        vtbf[(d4 + 2) * 2048 + p] = f2bf(x.z);
        vtbf[(d4 + 3) * 2048 + p] = f2bf(x.w);
    }
}

// ---------- Kernel B: compressed attention + top-k block select ----------
__global__ __launch_bounds__(256) void k_cmp_attn(const float* __restrict__ q,
                                                  const float* __restrict__ ck,
                                                  const float* __restrict__ cv,
                                                  float* __restrict__ o_cmp,
                                                  unsigned int* __restrict__ selmask) {
    __shared__ float sc[64 * 132];
    __shared__ float pg[TB * 128];
    __shared__ float slc[TB * 32];
    __shared__ float adj[TB * 32];
    int t0 = blockIdx.x * TB;
    int tid = threadIdx.x;
    int wv = tid >> 6, ln = tid & 63;

    {
        int rh = wv >> 1, nh = wv & 1;
        int rg = ln >> 3, ds = ln & 7;
        int d0 = ds * 16;
        float4 qr[4][4];
        #pragma unroll
        for (int rr = 0; rr < 4; ++rr) {
            int r = rh * 32 + rg * 4 + rr;
            const float4* qp = reinterpret_cast<const float4*>(
                q + (t0 + (r >> 3)) * 1024 + (r & 7) * 128 + d0);
            #pragma unroll
            for (int cc = 0; cc < 4; ++cc) qr[rr][cc] = qp[cc];
        }
        for (int jn = 0; jn < 64; ++jn) {
            int n = nh * 64 + jn;
            if (n >= NCMP) break;
            const float4* kp = reinterpret_cast<const float4*>(ck + n * 128 + d0);
            float4 k0 = kp[0], k1 = kp[1], k2 = kp[2], k3 = kp[3];
            float part[4];
            #pragma unroll
            for (int rr = 0; rr < 4; ++rr)
                part[rr] = dot4(qr[rr][0], k0) + dot4(qr[rr][1], k1) +
                           dot4(qr[rr][2], k2) + dot4(qr[rr][3], k3);
            #pragma unroll
            for (int off = 1; off < 8; off <<= 1)
                #pragma unroll
                for (int rr = 0; rr < 4; ++rr) part[rr] += __shfl_xor(part[rr], off);
            if (ds == 0) {
                #pragma unroll
                for (int rr = 0; rr < 4; ++rr)
                    sc[(rh * 32 + rg * 4 + rr) * 132 + n] = part[rr] * SCALE;
            }
        }
    }
    __syncthreads();

    {
        int r = wv * 16 + (ln >> 2);
        int nl = ln & 3;
        int t = t0 + (r >> 3);
        int nvalid = (t >= 31) ? (((t - 31) >> 4) + 1) : 0;
        if (nvalid > NCMP) nvalid = NCMP;
        float* row = sc + r * 132;
        float m = -3e38f;
        for (int n = nl; n < nvalid; n += 4) m = fmaxf(m, row[n]);
        m = fmaxf(m, __shfl_xor(m, 1));
        m = fmaxf(m, __shfl_xor(m, 2));
        float ss = 0.f;
        for (int n = nl; n < 128; n += 4) {
            float e = (n < nvalid) ? expf(row[n] - m) : 0.f;
            ss += e;
            row[n] = e;
        }
        ss += __shfl_xor(ss, 1);
        ss += __shfl_xor(ss, 2);
        float inv = (ss > 0.f) ? 1.f / ss : 0.f;
        for (int n = nl; n < 128; n += 4) row[n] *= inv;
    }
    __syncthreads();

    {
        int rg = ln >> 3, ds = ln & 7, d0 = ds * 16;
        int rbase = wv * 16 + rg * 2;
        int nvmax = (t0 + 7 >= 31) ? (((t0 + 7 - 31) >> 4) + 1) : 0;
        if (nvmax > NCMP) nvmax = NCMP;
        float4 acc[2][4];
        #pragma unroll
        for (int rr = 0; rr < 2; ++rr)
            #pragma unroll
            for (int cc = 0; cc < 4; ++cc) acc[rr][cc] = (float4){0.f, 0.f, 0.f, 0.f};
        for (int n = 0; n < nvmax; ++n) {
            const float4* vp = reinterpret_cast<const float4*>(cv + n * 128 + d0);
            float4 v0 = vp[0], v1 = vp[1], v2 = vp[2], v3 = vp[3];
            #pragma unroll
            for (int rr = 0; rr < 2; ++rr) {
                float p = sc[(rbase + rr) * 132 + n];
                acc[rr][0].x += p * v0.x; acc[rr][0].y += p * v0.y; acc[rr][0].z += p * v0.z; acc[rr][0].w += p * v0.w;
                acc[rr][1].x += p * v1.x; acc[rr][1].y += p * v1.y; acc[rr][1].z += p * v1.z; acc[rr][1].w += p * v1.w;
                acc[rr][2].x += p * v2.x; acc[rr][2].y += p * v2.y; acc[rr][2].z += p * v2.z; acc[rr][2].w += p * v2.w;
                acc[rr][3].x += p * v3.x; acc[rr][3].y += p * v3.y; acc[rr][3].z += p * v3.z; acc[rr][3].w += p * v3.w;
            }
        }
        #pragma unroll
        for (int rr = 0; rr < 2; ++rr) {
            int r = rbase + rr;
            float4* op = reinterpret_cast<float4*>(
                o_cmp + (t0 + (r >> 3)) * 1024 + (r & 7) * 128 + d0);
            #pragma unroll
            for (int cc = 0; cc < 4; ++cc) op[cc] = acc[rr][cc];
        }
    }

    for (int i2 = tid; i2 < TB * 128; i2 += 256) {
        int tl = i2 >> 7, n = i2 & 127;
        float s = 0.f;
        #pragma unroll
        for (int h = 0; h < 8; ++h) s += sc[(tl * 8 + h) * 132 + n];
        pg[i2] = s;
    }
    __syncthreads();
    if (tid < TB * 32) {
        int tl = tid >> 5, s32 = tid & 31;
        float s = 0.f;
        #pragma unroll
        for (int j = 0; j < 4; ++j) {
            int n = s32 * 4 + j;
            if (n < NCMP) s += pg[tl * 128 + n];
        }
        slc[tid] = s;
    }
    __syncthreads();
    if (tid < TB) {
        int t = t0 + tid;
        int qblk = t >> 6;
        float* a = adj + tid * 32;
        for (int s = 0; s < 32; ++s) {
            if (s > qblk) a[s] = -1e30f;
            else a[s] = slc[tid * 32 + s] + ((s == 0 || s > qblk - 2) ? 1e30f : 0.f);
        }
        unsigned int msk = 0u;
        for (int it = 0; it < 16; ++it) {
            float best = -2e38f; int bi = 0;
            for (int s = 0; s < 32; ++s) { if (a[s] > best) { best = a[s]; bi = s; } }
            if (best <= -5e29f) break;
            msk |= 1u << bi;
            a[bi] = -2e38f;
        }
        selmask[t] = msk;
    }
}

// -------- Kernel C: swapped-operand NSA attention; waves 0,1 sel / 2,3 win --------
__global__ __launch_bounds__(256, 4) void k_main(const float* __restrict__ q,
                                              const unsigned short* __restrict__ kbf,
                                              const unsigned short* __restrict__ vtbf,
                                              const unsigned int* __restrict__ selmask,
                                              const float* __restrict__ fw,
                                              float* __restrict__ out) {
    __shared__ float mrg[2][16 * 132];             // per-branch merge buffers
    __shared__ float mlbuf[4][16][2];              // wave, row, {m,l}

    int bid = blockIdx.x;
    int pairidx = ((bid & 255) << 2) | (bid >> 8);
    int tp = pairidx * 2;

    int tid = threadIdx.x;
    int wv = tid >> 6, ln = tid & 63;
    int c = ln & 15, g = ln >> 4;
    bool is_sel = (wv < 2);
    int w = wv & 1;              // split-K parity within branch

    unsigned int sm0 = selmask[tp], sm1 = selmask[tp + 1];
    unsigned int sm_wave = sm0 | sm1;

    // per-lane q-row: row = c -> t = tp + (c>>3), h = c&7
    int th = tp + (c >> 3);
    int hh = c & 7;
    unsigned int smc = (c >> 3) ? sm1 : sm0;

    // Q fragments (B-operand for swapped QK), pre-scaled to log2 domain
    bf16x8 qf[4];
    {
        const float* qp = q + th * 1024 + hh * 128;
        #pragma unroll
        for (int ks = 0; ks < 4; ++ks) {
            int d0 = ks * 32 + g * 8;
            float4 x = *reinterpret_cast<const float4*>(qp + d0);
            float4 y = *reinterpret_cast<const float4*>(qp + d0 + 4);
            bf16x8 f;
            f[0]=(short)f2bf(x.x*QSCALE); f[1]=(short)f2bf(x.y*QSCALE); f[2]=(short)f2bf(x.z*QSCALE); f[3]=(short)f2bf(x.w*QSCALE);
            f[4]=(short)f2bf(y.x*QSCALE); f[5]=(short)f2bf(y.y*QSCALE); f[6]=(short)f2bf(y.z*QSCALE); f[7]=(short)f2bf(y.w*QSCALE);
            qf[ks] = f;
        }
    }

    float m_run = -1e30f, l_run = 0.f;
    f32x4 o_acc[8];
    #pragma unroll
    for (int dt = 0; dt < 8; ++dt) o_acc[dt] = (f32x4){0.f, 0.f, 0.f, 0.f};

    int qblk_max = (tp + 1) >> 6;
    int srcA = ((g & 1) << 5) + c;   // lane (c, 2*(g&1))
    int srcB = srcA + 16;
    bool hi = (g >= 2);

    auto process = [&](int b) {
        // QK^T swapped: S[qrow=c][pos = b*64 + nt*16 + g*4 + i]
        f32x4 sacc[4];
        #pragma unroll
        for (int nt = 0; nt < 4; ++nt) {
            f32x4 acc = (f32x4){0.f, 0.f, 0.f, 0.f};
            #pragma unroll
            for (int ks = 0; ks < 4; ++ks) {
                bf16x8 bfK = *reinterpret_cast<const bf16x8*>(
                    kbf + (b * 64 + nt * 16 + c) * 128 + ks * 32 + g * 8);
                acc = __builtin_amdgcn_mfma_f32_16x16x32_bf16(bfK, qf[ks], acc, 0, 0, 0);
            }
            sacc[nt] = acc;
        }

        // mask + in-lane max (one q-row per lane)
        bool selbit = (smc >> b) & 1u;
        float mloc = -1e30f;
        #pragma unroll
        for (int nt = 0; nt < 4; ++nt) {
            #pragma unroll
            for (int i = 0; i < 4; ++i) {
                int pos = b * 64 + nt * 16 + g * 4 + i;
                bool val;
                if (is_sel) val = selbit && (pos <= th);
                else        val = (pos <= th) && (pos + 512 > th);
                float s = val ? sacc[nt][i] : -1e30f;
                sacc[nt][i] = s;
                mloc = fmaxf(mloc, s);
            }
        }
        mloc = fmaxf(mloc, __shfl_xor(mloc, 16));
        mloc = fmaxf(mloc, __shfl_xor(mloc, 32));
        float mn = fmaxf(m_run, mloc);
        float al = exp2f(m_run - mn);

        float lsum = 0.f;
        #pragma unroll
        for (int nt = 0; nt < 4; ++nt) {
            #pragma unroll
            for (int i = 0; i < 4; ++i) {
                float s = sacc[nt][i];
                float p = (s > -5e29f) ? exp2f(s - mn) : 0.f;
                sacc[nt][i] = p;
                lsum += p;
            }
        }
        lsum += __shfl_xor(lsum, 16);
        lsum += __shfl_xor(lsum, 32);
        m_run = mn;
        l_run = l_run * al + lsum;

        if (__any(al != 1.f)) {
            #pragma unroll
            for (int dt = 0; dt < 8; ++dt)
                #pragma unroll
                for (int i = 0; i < 4; ++i)
                    o_acc[dt][i] *= al;
        }

        // pack P rows to bf16 pairs: pw[2*nt] = (p0,p1), pw[2*nt+1] = (p2,p3)
        unsigned int pw[8];
        #pragma unroll
        for (int nt = 0; nt < 4; ++nt) {
            unsigned int w0, w1;
            asm("v_cvt_pk_bf16_f32 %0, %1, %2" : "=v"(w0) : "v"(sacc[nt][0]), "v"(sacc[nt][1]));
            asm("v_cvt_pk_bf16_f32 %0, %1, %2" : "=v"(w1) : "v"(sacc[nt][2]), "v"(sacc[nt][3]));
            pw[2 * nt] = w0;
            pw[2 * nt + 1] = w1;
        }

        // in-register P^T B-frag assembly + PV (swapped: A = V^T tile)
        #pragma unroll
        for (int ks = 0; ks < 2; ++ks) {
            unsigned int a0 = __shfl(pw[4 * ks + 0], srcA);
            unsigned int a1 = __shfl(pw[4 * ks + 1], srcA);
            unsigned int a2 = __shfl(pw[4 * ks + 0], srcB);
            unsigned int a3 = __shfl(pw[4 * ks + 1], srcB);
            unsigned int b0 = __shfl(pw[4 * ks + 2], srcA);
            unsigned int b1 = __shfl(pw[4 * ks + 3], srcA);
            unsigned int b2 = __shfl(pw[4 * ks + 2], srcB);
            unsigned int b3 = __shfl(pw[4 * ks + 3], srcB);
            unsigned int wp0 = hi ? b0 : a0;
            unsigned int wp1 = hi ? b1 : a1;
            unsigned int wp2 = hi ? b2 : a2;
            unsigned int wp3 = hi ? b3 : a3;
            unsigned int wparr[4] = {wp0, wp1, wp2, wp3};
            bf16x8 pa = *reinterpret_cast<bf16x8*>(wparr);
            #pragma unroll
            for (int dt = 0; dt < 8; ++dt) {
                bf16x8 bfV = *reinterpret_cast<const bf16x8*>(
                    vtbf + (dt * 16 + c) * 2048 + b * 64 + ks * 32 + g * 8);
                o_acc[dt] = __builtin_amdgcn_mfma_f32_16x16x32_bf16(bfV, pa, o_acc[dt], 0, 0, 0);
            }
        }
    };

    if (is_sel) {
        unsigned int mm = sm_wave;
        if (qblk_max < 31) mm &= (1u << (qblk_max + 1)) - 1u;
        int idx = 0;
        while (mm) {
            int b = __builtin_ctz(mm);
            mm &= mm - 1;
            if ((idx++ & 1) == w) process(b);
        }
    } else {
        int wlo = (tp >= 575) ? (((tp - 575) >> 6) + 1) : 0;
        for (int b = wlo + w; b <= qblk_max; b += 2) process(b);
    }

    // ---- merge: wave1 -> wave0 (select), wave3 -> wave2 (window) ----
    if (w == 1) {
        if (g == 0) { mlbuf[wv][c][0] = m_run; mlbuf[wv][c][1] = l_run; }
        #pragma unroll
        for (int dt = 0; dt < 8; ++dt)
            *reinterpret_cast<float4*>(&mrg[wv >> 1][c * 132 + dt * 16 + g * 4]) =
                (float4){o_acc[dt][0], o_acc[dt][1], o_acc[dt][2], o_acc[dt][3]};
    }
    __syncthreads();
    if (w == 0) {
        float m1 = mlbuf[wv + 1][c][0];
        float l1 = mlbuf[wv + 1][c][1];
        float mn = fmaxf(m_run, m1);
        float a0 = exp2f(m_run - mn), a1 = exp2f(m1 - mn);
        l_run = a0 * l_run + a1 * l1;
        float inv = 1.f / l_run;
        #pragma unroll
        for (int dt = 0; dt < 8; ++dt) {
            float4 o1 = *reinterpret_cast<const float4*>(&mrg[wv >> 1][c * 132 + dt * 16 + g * 4]);
            o_acc[dt][0] = (a0 * o_acc[dt][0] + a1 * o1.x) * inv;
            o_acc[dt][1] = (a0 * o_acc[dt][1] + a1 * o1.y) * inv;
            o_acc[dt][2] = (a0 * o_acc[dt][2] + a1 * o1.z) * inv;
            o_acc[dt][3] = (a0 * o_acc[dt][3] + a1 * o1.w) * inv;
        }
    }
    // wave 2 publishes final (normalized) o_sw
    if (wv == 2) {
        #pragma unroll
        for (int dt = 0; dt < 8; ++dt)
            *reinterpret_cast<float4*>(&mrg[1][c * 132 + dt * 16 + g * 4]) =
                (float4){o_acc[dt][0], o_acc[dt][1], o_acc[dt][2], o_acc[dt][3]};
    }
    __syncthreads();
    if (wv != 0) return;

    // ---- fusion epilogue (wave 0: o_sel in regs, o_sw in mrg[1], o_cmp in out) ----
    float4 oc[8], ow[8];
    #pragma unroll
    for (int dt = 0; dt < 8; ++dt) {
        oc[dt] = *reinterpret_cast<const float4*>(out + th * 1024 + hh * 128 + dt * 16 + g * 4);
        ow[dt] = *reinterpret_cast<const float4*>(&mrg[1][c * 132 + dt * 16 + g * 4]);
    }
    const float* fwp = fw + hh * 3 * 384;
    float p0 = 0.f, p1 = 0.f, p2 = 0.f;
    #pragma unroll
    for (int dt = 0; dt < 8; ++dt) {
        #pragma unroll
        for (int i = 0; i < 4; ++i) {
            int d = dt * 16 + g * 4 + i;
            float a = (i == 0) ? oc[dt].x : (i == 1) ? oc[dt].y : (i == 2) ? oc[dt].z : oc[dt].w;
            float bsl = o_acc[dt][i];
            float cw = (i == 0) ? ow[dt].x : (i == 1) ? ow[dt].y : (i == 2) ? ow[dt].z : ow[dt].w;
            p0 += fwp[0 * 384 + d] * a + fwp[0 * 384 + 128 + d] * bsl + fwp[0 * 384 + 256 + d] * cw;
            p1 += fwp[1 * 384 + d] * a + fwp[1 * 384 + 128 + d] * bsl + fwp[1 * 384 + 256 + d] * cw;
            p2 += fwp[2 * 384 + d] * a + fwp[2 * 384 + 128 + d] * bsl + fwp[2 * 384 + 256 + d] * cw;
        }
    }
    p0 += __shfl_xor(p0, 16); p0 += __shfl_xor(p0, 32);
    p1 += __shfl_xor(p1, 16); p1 += __shfl_xor(p1, 32);
    p2 += __shfl_xor(p2, 16); p2 += __shfl_xor(p2, 32);
    float mx = fmaxf(p0, fmaxf(p1, p2));
    float e0 = expf(p0 - mx), e1 = expf(p1 - mx), e2 = expf(p2 - mx);
    float inv3 = 1.f / (e0 + e1 + e2);
    float w0 = e0 * inv3, w1 = e1 * inv3, w2 = e2 * inv3;
    #pragma unroll
    for (int dt = 0; dt < 8; ++dt) {
        float4 r;
        r.x = w0 * oc[dt].x + w1 * o_acc[dt][0] + w2 * ow[dt].x;
        r.y = w0 * oc[dt].y + w1 * o_acc[dt][1] + w2 * ow[dt].y;
        r.z = w0 * oc[dt].z + w1 * o_acc[dt][2] + w2 * ow[dt].z;
        r.w = w0 * oc[dt].w + w1 * o_acc[dt][3] + w2 * ow[dt].w;
        *reinterpret_cast<float4*>(out + th * 1024 + hh * 128 + dt * 16 + g * 4) = r;
    }
}

extern "C" void kernel_launch(void* const* d_in, const int* in_sizes, int n_in,
                              void* d_out, int out_size, void* d_ws, size_t ws_size,
                              hipStream_t stream) {
    (void)in_sizes; (void)n_in; (void)out_size; (void)ws_size;
    const float* q   = (const float*)d_in[0];
    const float* k   = (const float*)d_in[1];
    const float* v   = (const float*)d_in[2];
    const float* wk  = (const float*)d_in[3];
    const float* wvg = (const float*)d_in[4];
    const float* fw  = (const float*)d_in[5];
    float* out = (float*)d_out;
    float* ws = (float*)d_ws;
    float* ck = ws;
    float* cv = ws + NCMP * 128;
    unsigned int* selmask = (unsigned int*)(ws + 2 * NCMP * 128);
    unsigned short* kbf = (unsigned short*)(ws + 2 * NCMP * 128 + 2048);
    unsigned short* vtbf = kbf + 2048 * 128;

    k_convert<<<dim3(256), dim3(256), 0, stream>>>(k, v, kbf, vtbf);
    k_compress2<<<dim3(2 * NCMP), dim3(256), 0, stream>>>(k, v, wk, wvg, ck, cv);
    k_cmp_attn<<<dim3(2048 / TB), dim3(256), 0, stream>>>(q, ck, cv, out, selmask);
    k_main<<<dim3(1024), dim3(256), 0, stream>>>(q, kbf, vtbf, selmask, fw, out);
}